// Round 13
// baseline (13564.006 us; speedup 1.0000x reference)
//
#include <hip/hip_runtime.h>
#include <hip/hip_bf16.h>
#include <math.h>

// PRNN round 13: r12 skeleton + (1) coalesced 16B publish/mirror (per-WG
// contiguous 4KB pub blocks, dwordx4 sc0sc1) + (2) enc = x@Wenc^T precomputed
// LAG=4 steps ahead by kc1 waves into a local ring (off critical path); main
// GEMM is K=2048 split 512/wave; own-half waves poll floc only, partner-half
// waves poll fmir only (per-wave entry). dec in its r10-proven slot.
// y_t = h_t@Wdec^T + b_dec ; h_t = (1-s)h_{t-1} + s*a*tanh(enc_t + b + h_{t-1}@Wrec^T)

#define B_   256
#define T_   512
#define NI_  512
#define NH_  2048
#define NO_  256

typedef __bf16 bf16_t;
typedef __bf16 bf16x8 __attribute__((ext_vector_type(8)));
typedef float  f32x4  __attribute__((ext_vector_type(4)));

#define MFMA16(a,b,c) __builtin_amdgcn_mfma_f32_16x16x32_bf16((a),(b),(c),0,0,0)
#define XCC_HWREG_IMM (20 | (31 << 11))

__device__ __forceinline__ void ld_sc0_x4(bf16x8& d, const void* p) {
  asm volatile("global_load_dwordx4 %0, %1, off sc0" : "=v"(d) : "v"(p));
}
__device__ __forceinline__ void ld_sc0_f4(f32x4& d, const void* p) {
  asm volatile("global_load_dwordx4 %0, %1, off sc0" : "=v"(d) : "v"(p));
}
__device__ __forceinline__ void ld_sc01_x4(bf16x8& d, const void* p) {
  asm volatile("global_load_dwordx4 %0, %1, off sc0 sc1" : "=v"(d) : "v"(p));
}
__device__ __forceinline__ void st_sc01_x4(void* p, bf16x8 v) {
  asm volatile("global_store_dwordx4 %0, %1, off sc0 sc1" :: "v"(p), "v"(v));
}
#define WAIT_VM0() do { asm volatile("s_waitcnt vmcnt(0)" ::: "memory"); \
                        __builtin_amdgcn_sched_barrier(0); } while (0)
#define WAIT_VM(n) do { asm volatile("s_waitcnt vmcnt(" #n ")" ::: "memory"); \
                        __builtin_amdgcn_sched_barrier(0); } while (0)

__device__ __forceinline__ void spin_ge(int* p, int tgt) {
  while (__hip_atomic_load(p, __ATOMIC_RELAXED, __HIP_MEMORY_SCOPE_AGENT) < tgt)
    __builtin_amdgcn_s_sleep(8);
}
__device__ __forceinline__ void bump(int* p) {
  __hip_atomic_fetch_add(p, 1, __ATOMIC_RELAXED, __HIP_MEMORY_SCOPE_AGENT);
}

// per-WG flag arrays (64B-strided ints) — r12-proven
__device__ __forceinline__ int* fA_loc(int* s, int x, int r) { return s + (x*32 + r)*16; }
__device__ __forceinline__ int* fA_mir(int* s, int x, int r) { return s + 4096 + (x*32 + r)*16; }
__device__ __forceinline__ int* fA_pub(int* s, int x, int r) { return s + 8192 + (x*32 + r)*16; }

__global__ __launch_bounds__(256) void k_cvt(const float* __restrict__ src,
                                             bf16_t* __restrict__ dst, int n) {
  int i = blockIdx.x * 256 + threadIdx.x;
  const int stride = gridDim.x * 256;
  for (; i < n; i += stride) dst[i] = (bf16_t)src[i];
}

// Decoder: 16x16 y-tile, K=2048 over 16 waves (r10/r12-proven)
__device__ __forceinline__ void dec_tile(
    int tid, int side, int rank, int rg,
    const bf16_t* hl, const bf16_t* hm,
    const bf16_t* __restrict__ Wdec, const float* __restrict__ b_dec,
    float* __restrict__ y_out, float* Scr)
{
  const int lane = tid & 63, w = tid >> 6, fl = lane & 15, kg = lane >> 4;
  const int drl = side*32 + (rank >> 4)*16;
  const int dc  = (rank & 15) * 16;
  const bf16_t* hbase = ((w >> 3) == side) ? hl : hm;
  const int kb = (w & 7) * 128;
  bf16x8 hf[4];
  #pragma unroll
  for (int i = 0; i < 4; ++i)
    ld_sc0_x4(hf[i], hbase + (size_t)(drl + fl)*1024 + kb + i*32 + kg*8);
  WAIT_VM0();
  f32x4 d = {0.f, 0.f, 0.f, 0.f};
  #pragma unroll
  for (int i = 0; i < 4; ++i) {
    bf16x8 wf = *reinterpret_cast<const bf16x8*>(
        Wdec + (size_t)(dc + fl)*NH_ + w*128 + i*32 + kg*8);
    d = MFMA16(hf[i], wf, d);
  }
  __syncthreads();
  #pragma unroll
  for (int j = 0; j < 4; ++j) Scr[w*256 + (kg*4 + j)*16 + fl] = d[j];
  __syncthreads();
  if (tid < 256) {
    const int r = tid >> 4, c = tid & 15;
    float s = b_dec[dc + c];
    #pragma unroll
    for (int ww = 0; ww < 16; ++ww) s += Scr[ww*256 + r*16 + c];
    y_out[(size_t)(rg*64 + drl + r)*NO_ + dc + c] = s;
  }
}

__global__ __launch_bounds__(1024, 1) void k_prnn(
    const float* __restrict__ x,
    const float* __restrict__ dt_p, const float* __restrict__ a_p,
    const float* __restrict__ Wrec,
    const bf16_t* __restrict__ Wenc_b, const bf16_t* __restrict__ Wdec_b,
    const float* __restrict__ b_rec, const float* __restrict__ b_enc,
    const float* __restrict__ b_dec,
    bf16_t* __restrict__ hloc, bf16_t* __restrict__ hmir,
    bf16_t* __restrict__ pub, float* __restrict__ enc_ring,
    int* __restrict__ sync_, float* __restrict__ out)
{
  __shared__ alignas(16) bf16x8 Wl[256 * 32];  // 128KB: [K-granule][col]
  __shared__ alignas(16) float  Scr[6144];     // 24KB: reduce / dec scratch
  __shared__ alignas(16) bf16_t Ts[2048];      // 4KB:  h-tile [64 rows][32 cols]
  __shared__ int sh_xcd, sh_rank;

  const int tid  = threadIdx.x;
  const int lane = tid & 63;
  const int fl   = lane & 15;
  const int kg   = lane >> 4;
  const int w    = tid >> 6;   // wave 0..15
  const int rt   = w & 3;      // row tile (16 rows)
  const int kc   = w >> 2;     // K quarter class (512 each)

  // ---- registration (r9/r10/r12-proven)
  if (tid == 0) {
    const int xc = (int)(__builtin_amdgcn_s_getreg(XCC_HWREG_IMM) & 7u);
    int* reg = sync_ + 12288 + xc * 16;
    const int rk = __hip_atomic_fetch_add(reg, 1, __ATOMIC_RELAXED, __HIP_MEMORY_SCOPE_AGENT);
    __hip_atomic_fetch_add(sync_ + 12416, 1, __ATOMIC_RELAXED, __HIP_MEMORY_SCOPE_AGENT);
    spin_ge(sync_ + 12416, 256);
    sh_xcd = xc; sh_rank = rk;
  }
  __syncthreads();
  const int xcd = sh_xcd, rank = sh_rank;
  if (rank >= 32) return;            // 1 WG/CU (proven); miss => loud hang
  const int rg = xcd >> 1, side = xcd & 1;

  bf16_t* hloc_x = hloc + (size_t)xcd * 4 * 65536;
  bf16_t* hmir_x = hmir + (size_t)xcd * 4 * 65536;
  bf16_t* pub_own = pub + (size_t)xcd * 2 * 65536;
  bf16_t* pub_par = pub + (size_t)(xcd ^ 1) * 2 * 65536;
  float*  enc_base = enc_ring + (size_t)(xcd * 32 + rank) * 4 * 2048;

  const float sgate = 1.f / (1.f + expf(-dt_p[0]));
  const float av = a_p[0];
  const float gi = 1.f - sgate;
  const float sav = sgate * av;
  const int colbase = rank * 32;
  const int colg0 = side*1024 + colbase + fl;
  const int colg1 = colg0 + 16;
  const float bias0 = b_rec[colg0] + b_enc[colg0];
  const float bias1 = b_rec[colg1] + b_enc[colg1];
  const bf16_t* we0 = Wenc_b + (size_t)colg0 * NI_;
  const bf16_t* we1 = Wenc_b + (size_t)colg1 * NI_;
  const int lrow = rt*16 + fl;               // local A row (0..63)
  const int grow = rg*64 + lrow;             // global batch row

  f32x4 hr0 = {0.f,0.f,0.f,0.f}, hr1 = {0.f,0.f,0.f,0.f};  // master state (kc0)

  // enc compute for step tt into ring slot (kc1 waves): 16 rows x 32 cols, K=512
  auto enc_compute = [&](int tt, int slot) {
    f32x4 e0 = {0.f,0.f,0.f,0.f}, e1 = {0.f,0.f,0.f,0.f};
    const float* xr = x + ((size_t)grow * T_ + tt) * NI_;
    #pragma unroll 4
    for (int c = 0; c < 16; ++c) {
      const int kp = c*32 + kg*8;
      float4 u = *reinterpret_cast<const float4*>(xr + kp);
      float4 v = *reinterpret_cast<const float4*>(xr + kp + 4);
      bf16x8 a = {(bf16_t)u.x, (bf16_t)u.y, (bf16_t)u.z, (bf16_t)u.w,
                  (bf16_t)v.x, (bf16_t)v.y, (bf16_t)v.z, (bf16_t)v.w};
      e0 = MFMA16(a, *reinterpret_cast<const bf16x8*>(we0 + kp), e0);
      e1 = MFMA16(a, *reinterpret_cast<const bf16x8*>(we1 + kp), e1);
    }
    float* ep = enc_base + (size_t)slot * 2048 + (rt*64 + lane) * 8;
    *reinterpret_cast<f32x4*>(ep)     = e0;
    *reinterpret_cast<f32x4*>(ep + 4) = e1;
  };

  // ---- prologue: W_rec slice (32 cols x 2048) -> LDS [granule][col]  (r10)
  {
    const int c = tid >> 5, part = tid & 31;
    const int cglob = side*1024 + colbase + c;
    #pragma unroll
    for (int i = 0; i < 8; ++i) {
      const int g = part*8 + i;              // 0..255
      const float* src = Wrec + (size_t)cglob * NH_ + g*8;
      float4 f0 = reinterpret_cast<const float4*>(src)[0];
      float4 f1 = reinterpret_cast<const float4*>(src)[1];
      bf16x8 w8 = {(bf16_t)f0.x, (bf16_t)f0.y, (bf16_t)f0.z, (bf16_t)f0.w,
                   (bf16_t)f1.x, (bf16_t)f1.y, (bf16_t)f1.z, (bf16_t)f1.w};
      Wl[g*32 + c] = w8;
    }
  }
  __syncthreads();
  // ---- prologue: enc(0..3) into ring slots 0..3
  if (kc == 1) {
    enc_compute(0, 0); enc_compute(1, 1); enc_compute(2, 2); enc_compute(3, 3);
  }
  __syncthreads();   // drains enc stores (per-wave vmcnt at barrier)

  #pragma unroll 1
  for (int t = 0; t < T_; ++t) {
    const int slotR = (t + 3) & 3;           // S_{t-1}
    const int slotW = t & 3;                 // S_t
    const int pslot = t & 1;

    // ---- per-wave entry: own-half waves need floc; partner-half need fmir
    if (kc < 2) { if (lane < 32) spin_ge(fA_loc(sync_, xcd, lane), t); }
    else        { if (lane < 32) spin_ge(fA_mir(sync_, xcd, lane), t); }

    const bf16_t* hl = hloc_x + (size_t)slotR * 65536;
    const bf16_t* hm = hmir_x + (size_t)slotR * 65536;

    // ---- GEMM: wave (rt,kc): 16 rows x 32 cols over its 512-K quarter
    f32x4 acc0 = {0.f,0.f,0.f,0.f}, acc1 = {0.f,0.f,0.f,0.f};
    {
      const bf16_t* hbuf = (kc < 2) ? hl : hm;
      const int gbase = ((kc < 2) ? side*128 : (side^1)*128) + (kc & 1)*64;
      const bf16_t* arow = hbuf + (size_t)lrow*1024 + (kc & 1)*512 + kg*8;
      bf16x8 pa[4];
      ld_sc0_x4(pa[0], arow);       ld_sc0_x4(pa[1], arow + 32);
      ld_sc0_x4(pa[2], arow + 64);  ld_sc0_x4(pa[3], arow + 96);
      #pragma unroll
      for (int c = 0; c < 16; ++c) {
        const int rem = 15 - c;
        if (rem >= 3)      { WAIT_VM(3); }
        else if (rem == 2) { WAIT_VM(2); }
        else if (rem == 1) { WAIT_VM(1); }
        else               { WAIT_VM0(); }
        const int gg = gbase + c*4 + kg;
        acc0 = MFMA16(pa[c & 3], Wl[gg*32 + fl], acc0);
        acc1 = MFMA16(pa[c & 3], Wl[gg*32 + 16 + fl], acc1);
        if (c + 4 < 16) ld_sc0_x4(pa[c & 3], arow + (size_t)(c + 4)*32);
      }
    }

    // ---- K-quarter reduce + gate (+enc from ring)
    __syncthreads();
    if (kc != 0) {
      const int base = (kc - 1)*2048 + rt*16*32;
      #pragma unroll
      for (int j = 0; j < 4; ++j) {
        Scr[base + (kg*4 + j)*32 + fl]      = acc0[j];
        Scr[base + (kg*4 + j)*32 + 16 + fl] = acc1[j];
      }
    }
    __syncthreads();
    if (kc == 0) {
      f32x4 e0, e1;
      const float* ep = enc_base + (size_t)(t & 3)*2048 + (rt*64 + lane)*8;
      ld_sc0_f4(e0, ep); ld_sc0_f4(e1, ep + 4);
      WAIT_VM0();
      #pragma unroll
      for (int j = 0; j < 4; ++j) {
        const int ri = (rt*16 + kg*4 + j)*32;
        const float v0 = acc0[j] + Scr[ri + fl] + Scr[2048 + ri + fl]
                                 + Scr[4096 + ri + fl] + e0[j];
        const float v1 = acc1[j] + Scr[ri + 16 + fl] + Scr[2048 + ri + 16 + fl]
                                 + Scr[4096 + ri + 16 + fl] + e1[j];
        const float o0 = gi*hr0[j] + sav*tanhf(v0 + bias0);
        const float o1 = gi*hr1[j] + sav*tanhf(v1 + bias1);
        hr0[j] = o0; hr1[j] = o1;
        Ts[(rt*16 + kg*4 + j)*32 + fl]      = (bf16_t)o0;
        Ts[(rt*16 + kg*4 + j)*32 + 16 + fl] = (bf16_t)o1;
        if (t == T_ - 1) {   // exact f32 final h from register master
          float* hd = out + (size_t)T_*B_*NO_ + (size_t)(rg*64 + rt*16 + kg*4 + j)*NH_;
          hd[colg0] = o0; hd[colg1] = o1;
        }
      }
    }
    __syncthreads();

    // ---- publish: hloc (plain 16B, local L2) + pub (contiguous 4KB, sc01 16B)
    if (tid < 256) {
      const int r = tid >> 2, c8 = (tid & 3) * 8;
      bf16x8 v = *reinterpret_cast<const bf16x8*>(&Ts[r*32 + c8]);
      *reinterpret_cast<bf16x8*>(hloc_x + (size_t)slotW*65536 + r*1024 + colbase + c8) = v;
      st_sc01_x4(pub_own + (size_t)pslot*65536 + rank*2048 + tid*8, v);
      WAIT_VM0();
    }
    __syncthreads();
    if (tid == 0)       bump(fA_loc(sync_, xcd, rank));      // uncontended RMW
    else if (tid == 64) bump(fA_pub(sync_, xcd, rank));      // uncontended RMW

    // ---- mirror partner's rank-matched 4KB block (contiguous sc01 16B reads)
    if (tid == 0) spin_ge(fA_pub(sync_, xcd ^ 1, rank), t + 1);
    __syncthreads();
    if (tid < 256) {
      bf16x8 mv;
      ld_sc01_x4(mv, pub_par + (size_t)pslot*65536 + rank*2048 + tid*8);
      WAIT_VM0();
      const int r = tid >> 2, c8 = (tid & 3) * 8;
      *reinterpret_cast<bf16x8*>(hmir_x + (size_t)slotW*65536 + r*1024 + colbase + c8) = mv;
    }
    __syncthreads();             // drains mirror stores
    if (tid == 0) bump(fA_mir(sync_, xcd, rank));

    // ---- decoder y_{t-2} (r10-proven placement, off inter-WG critical path)
    if (t >= 2)
      dec_tile(tid, side, rank, rg,
               hloc_x + (size_t)((t + 2) & 3)*65536,
               hmir_x + (size_t)((t + 2) & 3)*65536,
               Wdec_b, b_dec, out + (size_t)(t - 2)*B_*NO_, Scr);

    // ---- enc for step t+4 into ring slot (t+4)&3 == t&3 (read earlier this step)
    if (kc == 1 && t + 4 < T_) enc_compute(t + 4, t & 3);
  }

  // ---- epilogue: y_{T-2} (slot 2) and y_{T-1} (slot 3)
  if (tid < 32)                    spin_ge(fA_loc(sync_, xcd, tid), T_);
  else if (tid >= 64 && tid < 96)  spin_ge(fA_mir(sync_, xcd, tid - 64), T_);
  __syncthreads();
  dec_tile(tid, side, rank, rg, hloc_x + (size_t)2*65536, hmir_x + (size_t)2*65536,
           Wdec_b, b_dec, out + (size_t)(T_ - 2)*B_*NO_, Scr);
  dec_tile(tid, side, rank, rg, hloc_x + (size_t)3*65536, hmir_x + (size_t)3*65536,
           Wdec_b, b_dec, out + (size_t)(T_ - 1)*B_*NO_, Scr);
}

extern "C" void kernel_launch(void* const* d_in, const int* in_sizes, int n_in,
                              void* d_out, int out_size, void* d_ws, size_t ws_size,
                              hipStream_t stream) {
  const float* x     = (const float*)d_in[0];
  const float* dt_p  = (const float*)d_in[1];
  const float* a_p   = (const float*)d_in[2];
  const float* W_enc = (const float*)d_in[3];
  const float* b_enc = (const float*)d_in[4];
  const float* W_rec = (const float*)d_in[5];
  const float* b_rec = (const float*)d_in[6];
  const float* W_dec = (const float*)d_in[7];
  const float* b_dec = (const float*)d_in[8];
  float* out = (float*)d_out;

  char* p = (char*)d_ws;
  bf16_t* hloc   = (bf16_t*)p;  p += (size_t)8*4*65536*2;     // 4MB
  bf16_t* hmir   = (bf16_t*)p;  p += (size_t)8*4*65536*2;     // 4MB
  bf16_t* pub    = (bf16_t*)p;  p += (size_t)8*2*65536*2;     // 2MB
  bf16_t* Wenc_b = (bf16_t*)p;  p += (size_t)NH_*NI_*2;       // 2MB
  bf16_t* Wdec_b = (bf16_t*)p;  p += (size_t)NO_*NH_*2;       // 1MB
  float*  enc    = (float*)p;   p += (size_t)256*4*2048*4;    // 8MB
  int*    sync_  = (int*)p;     p += 16384*4;                 // 64KB (~21MB total)

  hipMemsetAsync(hloc, 0, (size_t)8*4*65536*2, stream);       // slot 3 = S_{-1} = 0
  hipMemsetAsync(hmir, 0, (size_t)8*4*65536*2, stream);
  hipMemsetAsync(sync_, 0, 16384*4, stream);

  k_cvt<<<128, 256, 0, stream>>>(W_enc, Wenc_b, NH_ * NI_);
  k_cvt<<<64, 256, 0, stream>>>(W_dec, Wdec_b, NO_ * NH_);

  k_prnn<<<dim3(256), dim3(1024), 0, stream>>>(
      x, dt_p, a_p, W_rec, Wenc_b, Wdec_b, b_rec, b_enc, b_dec,
      hloc, hmir, pub, enc, sync_, out);
}